// Round 1
// baseline (100.913 us; speedup 1.0000x reference)
//
#include <hip/hip_runtime.h>

#define B_ 64
#define TX_ 2048
#define DA_ 256
#define DS_ 256
#define H_ 50

// Kernel 1: per-row score -> w = exp(tanh(relu(x@W1+b1)@W2+b2))
// grid 512 blocks x 256 threads; block handles 256 consecutive rows (same batch).
__global__ __launch_bounds__(256) void e_kernel(
    const float* __restrict__ a, const float* __restrict__ s,
    const float* __restrict__ W1, const float* __restrict__ b1,
    const float* __restrict__ W2, const float* __restrict__ b2,
    float* __restrict__ w_exp, float* __restrict__ out)
{
  __shared__ float c_sh[H_];
  __shared__ float w2_sh[H_];
  const int tid = threadIdx.x;
  const int blk = blockIdx.x;
  const int b = blk >> 3;  // 8 blocks per batch (2048/256)

  // zero the output accumulator (ctx_kernel atomically accumulates later)
  if (blk < B_) out[blk * DA_ + tid] = 0.0f;

  // per-batch bias: c[h] = b1[h] + sum_k s[b,k] * W1[DA_+k, h]
  {
    const int h4 = tid >> 2, kq = tid & 3;
    float cp = 0.0f;
    if (h4 < H_) {
      const float* srow = s + b * DS_;
      #pragma unroll 4
      for (int k = kq * 64; k < kq * 64 + 64; ++k)
        cp += srow[k] * W1[(size_t)(DA_ + k) * H_ + h4];
    }
    cp += __shfl_down(cp, 1);
    cp += __shfl_down(cp, 2);
    if (h4 < H_ && kq == 0) c_sh[h4] = cp + b1[h4];
    if (tid < H_) w2_sh[tid] = W2[tid];
  }
  __syncthreads();

  const int row = blk * 256 + tid;
  const float* arow = a + (size_t)row * DA_;

  float acc[H_];
  #pragma unroll
  for (int h = 0; h < H_; ++h) acc[h] = c_sh[h];

  // a-row (divergent, float4 vector loads) x W1 (wave-uniform -> scalar loads)
  for (int kc = 0; kc < DA_ / 4; ++kc) {
    const float4 av = *(const float4*)(arow + kc * 4);
    const float* wk = W1 + (size_t)(kc * 4) * H_;
    #pragma unroll
    for (int h = 0; h < H_; ++h) {
      acc[h] += av.x * wk[h] + av.y * wk[H_ + h]
              + av.z * wk[2 * H_ + h] + av.w * wk[3 * H_ + h];
    }
  }

  float e = b2[0];
  #pragma unroll
  for (int h = 0; h < H_; ++h) e += fmaxf(acc[h], 0.0f) * w2_sh[h];
  e = tanhf(e);
  // e in [-1,1] -> exp is safe without max subtraction; softmax = w / sum(w)
  w_exp[row] = __expf(e);
}

// Kernel 2: per (batch, time-chunk): recompute sum(w) over all 2048 t (cheap),
// weighted partial sum of a over 256 t, atomic accumulate scaled result.
// grid 512 blocks (64 b x 8 chunks) x 256 threads.
__global__ __launch_bounds__(256) void ctx_kernel(
    const float* __restrict__ a, const float* __restrict__ w_exp,
    float* __restrict__ out)
{
  __shared__ float wsm[TX_];
  __shared__ float red[256];
  const int tid = threadIdx.x;
  const int blk = blockIdx.x;
  const int b = blk >> 3;
  const int ch = blk & 7;

  const float* wb = w_exp + b * TX_;
  float local = 0.0f;
  #pragma unroll
  for (int i = 0; i < TX_ / 256; ++i) {
    const float v = wb[tid + i * 256];
    wsm[tid + i * 256] = v;
    local += v;
  }
  red[tid] = local;
  __syncthreads();
  for (int step = 128; step > 0; step >>= 1) {
    if (tid < step) red[tid] += red[tid + step];
    __syncthreads();
  }
  const float invS = 1.0f / red[0];

  // wave w (=tid/64) handles t = t0 + w + 4*i ; lanes cover d in float4s
  const int d4 = (tid & 63) * 4;
  const int trow = tid >> 6;
  const int t0 = ch * 256;
  float4 acc = {0.0f, 0.0f, 0.0f, 0.0f};
  const float* ab = a + ((size_t)b * TX_ + t0 + trow) * DA_ + d4;
  #pragma unroll 4
  for (int i = 0; i < 64; ++i) {
    const float4 av = *(const float4*)(ab + (size_t)(4 * i) * DA_);
    const float wv = wsm[t0 + trow + 4 * i];
    acc.x += wv * av.x;
    acc.y += wv * av.y;
    acc.z += wv * av.z;
    acc.w += wv * av.w;
  }
  float* o = out + b * DA_ + d4;
  atomicAdd(o + 0, acc.x * invS);
  atomicAdd(o + 1, acc.y * invS);
  atomicAdd(o + 2, acc.z * invS);
  atomicAdd(o + 3, acc.w * invS);
}

extern "C" void kernel_launch(void* const* d_in, const int* in_sizes, int n_in,
                              void* d_out, int out_size, void* d_ws, size_t ws_size,
                              hipStream_t stream) {
  const float* a  = (const float*)d_in[0];
  const float* s  = (const float*)d_in[1];
  const float* W1 = (const float*)d_in[2];
  const float* b1 = (const float*)d_in[3];
  const float* W2 = (const float*)d_in[4];
  const float* b2 = (const float*)d_in[5];
  float* out = (float*)d_out;
  float* w_exp = (float*)d_ws;  // B_*TX_ floats = 512 KB

  e_kernel<<<dim3(512), dim3(256), 0, stream>>>(a, s, W1, b1, W2, b2, w_exp, out);
  ctx_kernel<<<dim3(512), dim3(256), 0, stream>>>(a, w_exp, out);
}